// Round 1
// baseline (454.341 us; speedup 1.0000x reference)
//
#include <hip/hip_runtime.h>
#include <hip/hip_bf16.h>

// Problem constants
#define B_ 8
#define S_ 4096
#define H_ 512
#define O_ 1024   // 2*H

// ---------- helpers ----------
__device__ __forceinline__ float bf2f(unsigned short u) {
    return __uint_as_float(((unsigned)u) << 16);
}
__device__ __forceinline__ unsigned short f2bf(float f) {
    unsigned x = __float_as_uint(f);
    unsigned r = (x + 0x7fffu + ((x >> 16) & 1u)) >> 16;  // RNE
    return (unsigned short)r;
}
__device__ __forceinline__ float softplus_f(float x) {
    float sp = __logf(1.0f + __expf(x));
    return x > 15.0f ? x : sp;
}

using short8 = __attribute__((ext_vector_type(8))) short;
using f32x4  = __attribute__((ext_vector_type(4))) float;

// ---------- GEMM: noise = softplus(A(32768x512) * W(1024x512)^T + b) ----------
// Output split: n<512 -> Q (bf16), n>=512 -> R (bf16), both [32768 x 512] in ws.
#define TM 128
#define TN 128
#define BK 32
#define LDT 40   // padded LDS row length (bf16 elems): 32 + 8

__global__ __launch_bounds__(256)
void gemm_softplus(const float* __restrict__ A, const float* __restrict__ Wm,
                   const float* __restrict__ bias,
                   unsigned short* __restrict__ Qo, unsigned short* __restrict__ Ro) {
    __shared__ unsigned short As[TM * LDT];
    __shared__ unsigned short Bs[TN * LDT];

    const int bid = blockIdx.x;
    const int bn  = bid & 7;     // N/128 = 8  (consecutive blocks share A strip -> L2 reuse)
    const int bm  = bid >> 3;    // 256
    const int t    = threadIdx.x;
    const int wave = t >> 6;
    const int lane = t & 63;
    const int wm = (wave >> 1) * 64;
    const int wn = (wave & 1) * 64;
    const int l15 = lane & 15;
    const int l4  = lane >> 4;   // 0..3

    const int m0 = bm * TM;
    const int n0 = bn * TN;

    f32x4 acc[4][4] = {};

    for (int kc = 0; kc < 512; kc += BK) {
        // stage A and B tiles (fp32 global -> bf16 LDS)
#pragma unroll
        for (int i = 0; i < 4; ++i) {
            int g   = t + 256 * i;        // 0..1023
            int row = g >> 3;             // 0..127
            int c   = (g & 7) * 4;        // 0..28
            float4 va = *(const float4*)(A  + (size_t)(m0 + row) * 512 + kc + c);
            float4 vb = *(const float4*)(Wm + (size_t)(n0 + row) * 512 + kc + c);
            ushort4 pa, pb;
            pa.x = f2bf(va.x); pa.y = f2bf(va.y); pa.z = f2bf(va.z); pa.w = f2bf(va.w);
            pb.x = f2bf(vb.x); pb.y = f2bf(vb.y); pb.z = f2bf(vb.z); pb.w = f2bf(vb.w);
            *(ushort4*)&As[row * LDT + c] = pa;
            *(ushort4*)&Bs[row * LDT + c] = pb;
        }
        __syncthreads();

        short8 af[4], bf[4];
#pragma unroll
        for (int i = 0; i < 4; ++i) {
            af[i] = *(const short8*)&As[(wm + i * 16 + l15) * LDT + l4 * 8];
            bf[i] = *(const short8*)&Bs[(wn + i * 16 + l15) * LDT + l4 * 8];
        }
#pragma unroll
        for (int i = 0; i < 4; ++i)
#pragma unroll
            for (int j = 0; j < 4; ++j)
                acc[i][j] = __builtin_amdgcn_mfma_f32_16x16x32_bf16(af[i], bf[j], acc[i][j], 0, 0, 0);
        __syncthreads();
    }

    // epilogue: bias + softplus, split-store bf16
#pragma unroll
    for (int i = 0; i < 4; ++i) {
        const int mbase = m0 + wm + i * 16 + l4 * 4;
#pragma unroll
        for (int j = 0; j < 4; ++j) {
            const int nloc = n0 + wn + j * 16 + l15;
            const float bs = bias[nloc];
#pragma unroll
            for (int r = 0; r < 4; ++r) {
                const int m = mbase + r;
                float x  = acc[i][j][r] + bs;
                unsigned short v = f2bf(softplus_f(x));
                if (nloc < 512) Qo[(size_t)m * 512 + nloc]       = v;
                else            Ro[(size_t)m * 512 + nloc - 512] = v;
            }
        }
    }
}

// ---------- Chunked Kalman scan with warm-up ----------
// 16 chunks of 256 steps; chunks >0 warm up for 128 steps from state=z, P=0.1.
// Contraction (1-K)~0.4/step makes warm-up error < 1e-20.
#define CHUNK 256
#define WARM 128

__global__ __launch_bounds__(256)
void kalman_scan(const float* __restrict__ z,
                 const unsigned short* __restrict__ Qv,
                 const unsigned short* __restrict__ Rv,
                 float* __restrict__ out) {
    const int t     = threadIdx.x;
    const int hb    = blockIdx.x & 1;
    const int b     = (blockIdx.x >> 1) & 7;
    const int chunk = blockIdx.x >> 4;          // 0..15
    const int h     = (hb << 8) + t;            // 0..511
    const int s0    = chunk << 8;               // chunk*256
    const int sw    = (chunk == 0) ? 0 : (s0 - WARM);
    const size_t base = ((size_t)((b << 12) + sw)) * 512 + h;

    const float* zp = z + base;
    const unsigned short* qp = Qv + base;
    const unsigned short* rp = Rv + base;
    float* op = out + base;

    float state = zp[0];
    float P = 0.1f;

    const int nst   = (s0 + CHUNK) - sw;        // 256 or 384
    const int ng    = nst >> 3;                 // groups of 8
    const int skipg = (s0 - sw) >> 3;           // 0 or 16

    float zb[2][8], qb[2][8], rb[2][8];
#pragma unroll
    for (int u = 0; u < 8; ++u) {
        const int off = u * 512;
        zb[0][u] = zp[off];
        qb[0][u] = bf2f(qp[off]);
        rb[0][u] = bf2f(rp[off]);
    }

    for (int g = 0; g < ng; ++g) {
        const int cur = g & 1;
        if (g + 1 < ng) {
            const int nb = cur ^ 1;
            const int boff2 = (g + 1) * 8 * 512;
#pragma unroll
            for (int u = 0; u < 8; ++u) {
                const int off = boff2 + u * 512;
                zb[nb][u] = zp[off];
                qb[nb][u] = bf2f(qp[off]);
                rb[nb][u] = bf2f(rp[off]);
            }
        }
        const bool st = (g >= skipg);
        const int boff = g * 8 * 512;
#pragma unroll
        for (int u = 0; u < 8; ++u) {
            const float q  = qb[cur][u];
            const float r  = rb[cur][u];
            const float zz = zb[cur][u];
            const float Pp = P + q;
            const float rr = r + 1e-6f;
            const float D  = __builtin_amdgcn_rcpf(Pp + rr);
            const float K  = Pp * D;
            state = fmaf(K, zz - state, state);
            P = rr * K;
            if (st) op[boff + u * 512] = state;
        }
    }
}

extern "C" void kernel_launch(void* const* d_in, const int* in_sizes, int n_in,
                              void* d_out, int out_size, void* d_ws, size_t ws_size,
                              hipStream_t stream) {
    const float* lstm = (const float*)d_in[0];   // (8,4096,512) fp32
    const float* Wm   = (const float*)d_in[1];   // (1024,512)  fp32
    const float* bias = (const float*)d_in[2];   // (1024,)     fp32
    float* out = (float*)d_out;

    unsigned short* Qw = (unsigned short*)d_ws;                     // 32 MB
    unsigned short* Rw = Qw + (size_t)B_ * S_ * H_;                 // 32 MB

    // GEMM + softplus: grid = (M/128)*(N/128) = 256*8 = 2048
    hipLaunchKernelGGL(gemm_softplus, dim3(2048), dim3(256), 0, stream,
                       lstm, Wm, bias, Qw, Rw);

    // Scan: 2(h-halves) * 8(batch) * 16(chunks) = 256 blocks of 256 threads
    hipLaunchKernelGGL(kalman_scan, dim3(256), dim3(256), 0, stream,
                       lstm, Qw, Rw, out);
}

// Round 2
// 253.717 us; speedup vs baseline: 1.7907x; 1.7907x over previous
//
#include <hip/hip_runtime.h>
#include <hip/hip_bf16.h>

// Problem constants
#define B_ 8
#define S_ 4096
#define H_ 512
#define O_ 1024   // 2*H

// ---------- helpers ----------
__device__ __forceinline__ float bf2f(unsigned u16) {
    return __uint_as_float(u16 << 16);
}
__device__ __forceinline__ unsigned pk2bf(float x, float y) {
    __hip_bfloat162 h = __float22bfloat162_rn(make_float2(x, y));  // v_cvt_pk_bf16_f32
    return *reinterpret_cast<unsigned*>(&h);
}
__device__ __forceinline__ float softplus_f(float x) {
    float sp = __logf(1.0f + __expf(x));
    return x > 15.0f ? x : sp;
}

using short8 = __attribute__((ext_vector_type(8))) short;
using f32x4  = __attribute__((ext_vector_type(4))) float;
using f32x8  = __attribute__((ext_vector_type(8))) float;
using u32x8  = __attribute__((ext_vector_type(8))) unsigned;

// ---------- GEMM: noise = softplus(A(32768x512) * W(1024x512)^T + b) ----------
// Output: QR interleaved ushort2 [32768 x 512 x {q,r}] bf16 in ws.
#define TM 128
#define TN 128
#define BK 32
#define LDT 40   // padded LDS row length (bf16 elems): 32 + 8

__global__ __launch_bounds__(256)
void gemm_softplus(const float* __restrict__ A, const float* __restrict__ Wm,
                   const float* __restrict__ bias,
                   unsigned short* __restrict__ QR) {
    __shared__ unsigned short As[TM * LDT];
    __shared__ unsigned short Bs[TN * LDT];

    const int bid = blockIdx.x;
    const int bn  = bid & 7;     // N/128 = 8  (consecutive blocks share A strip -> L2 reuse)
    const int bm  = bid >> 3;    // 256
    const int t    = threadIdx.x;
    const int wave = t >> 6;
    const int lane = t & 63;
    const int wm = (wave >> 1) * 64;
    const int wn = (wave & 1) * 64;
    const int l15 = lane & 15;
    const int l4  = lane >> 4;   // 0..3

    const int m0 = bm * TM;
    const int n0 = bn * TN;

    f32x4 acc[4][4] = {};

    for (int kc = 0; kc < 512; kc += BK) {
        // stage A and B tiles (fp32 global -> bf16 LDS, packed HW convert)
#pragma unroll
        for (int i = 0; i < 4; ++i) {
            int g   = t + 256 * i;        // 0..1023
            int row = g >> 3;             // 0..127
            int c   = (g & 7) * 4;        // 0..28
            float4 va = *(const float4*)(A  + (size_t)(m0 + row) * 512 + kc + c);
            float4 vb = *(const float4*)(Wm + (size_t)(n0 + row) * 512 + kc + c);
            uint2 pa, pb;
            pa.x = pk2bf(va.x, va.y); pa.y = pk2bf(va.z, va.w);
            pb.x = pk2bf(vb.x, vb.y); pb.y = pk2bf(vb.z, vb.w);
            *(uint2*)&As[row * LDT + c] = pa;
            *(uint2*)&Bs[row * LDT + c] = pb;
        }
        __syncthreads();

        short8 af[4], bf[4];
#pragma unroll
        for (int i = 0; i < 4; ++i) {
            af[i] = *(const short8*)&As[(wm + i * 16 + l15) * LDT + l4 * 8];
            bf[i] = *(const short8*)&Bs[(wn + i * 16 + l15) * LDT + l4 * 8];
        }
#pragma unroll
        for (int i = 0; i < 4; ++i)
#pragma unroll
            for (int j = 0; j < 4; ++j)
                acc[i][j] = __builtin_amdgcn_mfma_f32_16x16x32_bf16(af[i], bf[j], acc[i][j], 0, 0, 0);
        __syncthreads();
    }

    // epilogue: bias + softplus, interleaved {q,r} bf16 store
#pragma unroll
    for (int i = 0; i < 4; ++i) {
        const int mbase = m0 + wm + i * 16 + l4 * 4;
#pragma unroll
        for (int j = 0; j < 4; ++j) {
            const int nloc = n0 + wn + j * 16 + l15;
            const float bs = bias[nloc];
#pragma unroll
            for (int r = 0; r < 4; ++r) {
                const int m = mbase + r;
                float x = acc[i][j][r] + bs;
                __hip_bfloat162 hv = __float22bfloat162_rn(make_float2(softplus_f(x), 0.f));
                unsigned short v = *reinterpret_cast<unsigned short*>(&hv);
                if (nloc < 512) QR[((size_t)m * 512 + nloc) * 2]             = v;
                else            QR[((size_t)m * 512 + (nloc - 512)) * 2 + 1] = v;
            }
        }
    }
}

// ---------- Chunked Kalman scan with warm-up ----------
// 32 chunks of 128 steps; chunks >0 warm up for 128 steps from state=z, P=0.1.
// Explicit register double-buffer (vector types, no dynamic indexing).
#define CHUNK 128
#define WARM 128

__global__ __launch_bounds__(256)
void kalman_scan(const float* __restrict__ z,
                 const unsigned short* __restrict__ QR,
                 float* __restrict__ out) {
    const int t     = threadIdx.x;
    const int hb    = blockIdx.x & 1;
    const int b     = (blockIdx.x >> 1) & 7;
    const int chunk = blockIdx.x >> 4;          // 0..31
    const int h     = (hb << 8) + t;            // 0..511
    const int s0    = chunk << 7;               // chunk*128
    const int sw    = (chunk == 0) ? 0 : (s0 - WARM);
    const size_t base = ((size_t)(b * S_ + sw)) * 512 + h;

    const float* zp = z + base;
    const unsigned* qrp = (const unsigned*)QR + base;
    float* op = out + base;

    float state = zp[0];
    float P = 0.1f;

    const int ng    = ((s0 + CHUNK) - sw) >> 3; // 16 or 32 groups of 8
    const int skipg = (s0 - sw) >> 3;           // 0 or 16

    f32x8 zc, zn;
    u32x8 qc, qn;
#pragma unroll
    for (int u = 0; u < 8; ++u) { zc[u] = zp[u * 512]; qc[u] = qrp[u * 512]; }

    for (int g = 0; g < ng; ++g) {
        if (g + 1 < ng) {
            const int off = (g + 1) * 4096;
#pragma unroll
            for (int u = 0; u < 8; ++u) {
                zn[u] = zp[off + u * 512];
                qn[u] = qrp[off + u * 512];
            }
        }
        const bool st   = (g >= skipg);
        const int  boff = g * 4096;
#pragma unroll
        for (int u = 0; u < 8; ++u) {
            const unsigned qr = qc[u];
            const float q  = bf2f(qr & 0xffffu);
            const float r  = bf2f(qr >> 16);
            const float Pp = P + q;
            const float rr = r + 1e-6f;
            const float K  = Pp * __builtin_amdgcn_rcpf(Pp + rr);
            state = fmaf(K, zc[u] - state, state);
            P = rr * K;
            if (st) op[boff + u * 512] = state;
        }
        zc = zn; qc = qn;
    }
}

extern "C" void kernel_launch(void* const* d_in, const int* in_sizes, int n_in,
                              void* d_out, int out_size, void* d_ws, size_t ws_size,
                              hipStream_t stream) {
    const float* lstm = (const float*)d_in[0];   // (8,4096,512) fp32
    const float* Wm   = (const float*)d_in[1];   // (1024,512)  fp32
    const float* bias = (const float*)d_in[2];   // (1024,)     fp32
    float* out = (float*)d_out;

    unsigned short* QRw = (unsigned short*)d_ws;   // interleaved {q,r} bf16, 64 MB

    // GEMM + softplus: grid = (M/128)*(N/128) = 256*8 = 2048
    hipLaunchKernelGGL(gemm_softplus, dim3(2048), dim3(256), 0, stream,
                       lstm, Wm, bias, QRw);

    // Scan: 2(h-halves) * 8(batch) * 32(chunks) = 512 blocks of 256 threads
    hipLaunchKernelGGL(kalman_scan, dim3(512), dim3(256), 0, stream,
                       lstm, QRw, out);
}